// Round 18
// baseline (122.526 us; speedup 1.0000x reference)
//
#include <hip/hip_runtime.h>

#define BB 2
#define SS 2048
#define EE 768
#define HH 12
#define DKK 64

typedef _Float16 h16;
typedef _Float16 half8 __attribute__((ext_vector_type(8)));
typedef _Float16 h16x4 __attribute__((ext_vector_type(4)));
typedef __fp16 pk2 __attribute__((ext_vector_type(2)));
typedef float f32x4 __attribute__((ext_vector_type(4)));

#define K2F 11.5416173f                        // 8 * log2(e): source multiplies by sqrt(dk)!

// direct global->LDS 16B async copy (linear LDS dest = wave base + lane*16)
__device__ __forceinline__ void gl_lds16(const void* g, void* l) {
    __builtin_amdgcn_global_load_lds(
        (const __attribute__((address_space(1))) unsigned int*)g,
        (__attribute__((address_space(3))) unsigned int*)l, 16, 0, 0);
}

// ---------------- fused: fp32->fp16 convert (blocks 0..5183) + mask packing (5184..5695) ----------------
__global__ void cvtpack_k(const float* __restrict__ sK, const float* __restrict__ sQ,
                          const float* __restrict__ sV, const float* __restrict__ sWk,
                          const float* __restrict__ sWo,
                          h16* __restrict__ dK, h16* __restrict__ dQ, h16* __restrict__ dV,
                          h16* __restrict__ dWk, h16* __restrict__ dWo,
                          const int* __restrict__ mask, unsigned* __restrict__ mp) {
    if (blockIdx.x >= 5184) {                  // mask packing: int32 [S,S] -> 1 bit
        int idx = (blockIdx.x - 5184) * 256 + threadIdx.x;
        int base = idx * 32;
        const int4* m4 = (const int4*)(mask + base);
        unsigned w = 0;
#pragma unroll
        for (int i = 0; i < 8; ++i) {
            int4 v = m4[i];
            if (v.x) w |= 1u << (i * 4 + 0);
            if (v.y) w |= 1u << (i * 4 + 1);
            if (v.z) w |= 1u << (i * 4 + 2);
            if (v.w) w |= 1u << (i * 4 + 3);
        }
        mp[idx] = w;
        return;
    }
    long g = (long)blockIdx.x * 256 + threadIdx.x;
    const float* src;
    h16* dst;
    long off;
    if (g < 393216)        { src = sK;  dst = dK;  off = g; }
    else if (g < 786432)   { src = sQ;  dst = dQ;  off = g - 393216; }
    else if (g < 1179648)  { src = sV;  dst = dV;  off = g - 786432; }
    else if (g < 1253376)  { src = sWk; dst = dWk; off = g - 1179648; }
    else                   { src = sWo; dst = dWo; off = g - 1253376; }
    const float* p = src + off * 8;
    float4 a = *(const float4*)p, b = *(const float4*)(p + 4);
    half8 h = {(h16)a.x, (h16)a.y, (h16)a.z, (h16)a.w,
               (h16)b.x, (h16)b.y, (h16)b.z, (h16)b.w};
    *(half8*)(dst + off * 8) = h;
}

// ---------------- projection GEMM: fp16 in, global_load_lds staging ----------------
__launch_bounds__(256)
__global__ void proj_gemm_k(const h16* __restrict__ keyh, const h16* __restrict__ qryh,
                            const h16* __restrict__ valh, const h16* __restrict__ Wkh,
                            const float* __restrict__ bk,
                            h16* __restrict__ kh, h16* __restrict__ qh, h16* __restrict__ vtp) {
    __shared__ h16 As[64 * 64];                     // 8 KB
    __shared__ h16 Bs[128 * 64];                    // 16 KB
    const int bid = blockIdx.x;                     // 0..1151
    const int idx = (bid & 7) * 144 + (bid >> 3);
    const int z = idx / 384;
    const int rem = idx % 384;
    const int m0 = (rem / 6) * 64, n0 = (rem % 6) * 128;
    const h16* src = (z == 0) ? keyh : ((z == 1) ? qryh : valh);
    const int tid = threadIdx.x, lane = tid & 63, wid = tid >> 6;
    const int l = lane & 15, gq = lane >> 4;
    f32x4 acc[4][2] = {};                           // wave: 64m x 32n

    for (int k0 = 0; k0 < EE; k0 += 64) {
#pragma unroll
        for (int it = 0; it < 2; ++it) {            // A: 64 rows
            int e = it * 256 + tid;
            int row = e >> 3, slot = e & 7;
            gl_lds16(src + (long)(m0 + row) * EE + k0 + ((slot ^ (row & 7)) << 3), As + e * 8);
        }
#pragma unroll
        for (int it = 0; it < 4; ++it) {            // B: 128 rows
            int e = it * 256 + tid;
            int row = e >> 3, slot = e & 7;
            gl_lds16(Wkh + (long)(n0 + row) * EE + k0 + ((slot ^ (row & 7)) << 3), Bs + e * 8);
        }
        __syncthreads();                            // drains vmcnt
#pragma unroll
        for (int ks = 0; ks < 2; ++ks) {
            half8 a[4], b[2];
#pragma unroll
            for (int rf = 0; rf < 4; ++rf) {
                int row = rf * 16 + l;
                int g = (ks * 4 + gq) ^ (row & 7);
                a[rf] = *(const half8*)((const char*)As + row * 128 + (g << 4));
            }
#pragma unroll
            for (int cf = 0; cf < 2; ++cf) {
                int row = wid * 32 + cf * 16 + l;
                int g = (ks * 4 + gq) ^ (row & 7);
                b[cf] = *(const half8*)((const char*)Bs + row * 128 + (g << 4));
            }
            __builtin_amdgcn_s_setprio(1);
#pragma unroll
            for (int rf = 0; rf < 4; ++rf)
#pragma unroll
                for (int cf = 0; cf < 2; ++cf)
                    acc[rf][cf] = __builtin_amdgcn_mfma_f32_16x16x32_f16(a[rf], b[cf], acc[rf][cf], 0, 0, 0);
            __builtin_amdgcn_s_setprio(0);
        }
        __syncthreads();
    }
    if (z == 2) {
        // V: write transposed vt[(b*H+h)*64 + d][s], 4 consecutive s packed
#pragma unroll
        for (int rf = 0; rf < 4; ++rf)
#pragma unroll
            for (int cf = 0; cf < 2; ++cf) {
                int n = n0 + wid * 32 + cf * 16 + l;
                float bias = bk[n];
                int h = n >> 6, d = n & 63;
                int mb = m0 + rf * 16 + gq * 4;
                int b = mb >> 11, s = mb & 2047;
                h16x4 pv = {(h16)(acc[rf][cf][0] + bias), (h16)(acc[rf][cf][1] + bias),
                            (h16)(acc[rf][cf][2] + bias), (h16)(acc[rf][cf][3] + bias)};
                *(h16x4*)(vtp + ((long)((b * HH + h) * 64 + d)) * SS + s) = pv;
            }
    } else {
        h16* dst = (z == 0) ? kh : qh;
        const float qs = (z == 1) ? K2F : 1.0f;     // pre-scale q into exp2 domain
#pragma unroll
        for (int rf = 0; rf < 4; ++rf)
#pragma unroll
            for (int cf = 0; cf < 2; ++cf) {
                int n = n0 + wid * 32 + cf * 16 + l;
                float bias = bk[n];
                int h = n >> 6, d = n & 63;
#pragma unroll
                for (int j = 0; j < 4; ++j) {
                    int m = m0 + rf * 16 + gq * 4 + j;
                    int b = m >> 11, s = m & 2047;
                    dst[(((long)(b * HH + h) * SS + s) << 6) + d] = (h16)((acc[rf][cf][j] + bias) * qs);
                }
            }
    }
}

// ---------------- flash attention: 4 waves x 32 q-rows (2 groups), kv-split-2, partials ----------------
#define SMX_GROUP(S, MW, M2, LS, PB)                                               \
  {                                                                                \
    unsigned long long mw = (MW);                                                  \
    unsigned w0 = (unsigned)mw, w1 = (unsigned)(mw >> 32);                         \
    _Pragma("unroll")                                                              \
    for (int cf = 0; cf < 4; ++cf) {                                               \
      unsigned wcb = (cf & 2) ? w1 : w0;                                           \
      _Pragma("unroll")                                                            \
      for (int j = 0; j < 4; ++j) {                                                \
        unsigned sh = ((cf & 1) << 4) + g * 4 + j;                                 \
        S[cf][j] = ((wcb >> sh) & 1u) ? S[cf][j] : C2;                             \
      }                                                                            \
    }                                                                              \
    float pmax = fmaxf(fmaxf(S[0][0], S[0][1]), fmaxf(S[0][2], S[0][3]));          \
    _Pragma("unroll")                                                              \
    for (int cf = 1; cf < 4; ++cf)                                                 \
      pmax = fmaxf(pmax, fmaxf(fmaxf(S[cf][0], S[cf][1]), fmaxf(S[cf][2], S[cf][3]))); \
    if (!__all(pmax <= (M2) + 11.0f)) {                                            \
      pmax = fmaxf(pmax, __shfl_xor(pmax, 16));                                    \
      pmax = fmaxf(pmax, __shfl_xor(pmax, 32));                                    \
      float mnew = fmaxf((M2), pmax);                                              \
      float alpha = __builtin_amdgcn_exp2f((M2) - mnew);                           \
      _Pragma("unroll")                                                            \
      for (int df = 0; df < 4; ++df)                                               \
        _Pragma("unroll")                                                          \
        for (int j = 0; j < 4; ++j) o##PB[df][j] *= alpha;                         \
      (LS) *= alpha;                                                               \
      (M2) = mnew;                                                                 \
    }                                                                              \
    const float negm2 = -(M2);                                                     \
    float rs0 = 0.f, rs1 = 0.f;                                                    \
    _Pragma("unroll")                                                              \
    for (int cf = 0; cf < 4; ++cf) {                                               \
      float p0 = __builtin_amdgcn_exp2f(S[cf][0] + negm2);                         \
      float p1 = __builtin_amdgcn_exp2f(S[cf][1] + negm2);                         \
      float p2 = __builtin_amdgcn_exp2f(S[cf][2] + negm2);                         \
      float p3 = __builtin_amdgcn_exp2f(S[cf][3] + negm2);                         \
      union { pk2 h[2]; unsigned long long u; } pu;                                \
      pu.h[0] = __builtin_amdgcn_cvt_pkrtz(p0, p1);                                \
      pu.h[1] = __builtin_amdgcn_cvt_pkrtz(p2, p3);                                \
      rs0 = __builtin_amdgcn_fdot2(pu.h[0], one2, rs0, false);                     \
      rs1 = __builtin_amdgcn_fdot2(pu.h[1], one2, rs1, false);                     \
      *(unsigned long long*)(pb##PB + pst[cf]) = pu.u;                             \
    }                                                                              \
    (LS) += rs0 + rs1;                                                             \
  }

#define ATTN_TILE(KL, VL, KN, VN, T)                                               \
  {                                                                                \
    long nko = (long)((((T) + 1) & 15)) * (64 * DKK);                              \
    int nvo = (((T) + 1) & 15) * 64;                                               \
    gl_lds16(kgl0 + nko, (KN) + stg0);                                             \
    gl_lds16(kgl1 + nko, (KN) + stg1);                                             \
    gl_lds16(vgl0 + nvo, (VN) + stg0);                                             \
    gl_lds16(vgl1 + nvo, (VN) + stg1);                                             \
    half8 ka[4], kb[4];                                                            \
    _Pragma("unroll")                                                              \
    for (int cf = 0; cf < 4; ++cf) {                                               \
      ka[cf] = *(const half8*)((const char*)(KL) + off0 + cf * 2048);              \
      kb[cf] = *(const half8*)((const char*)(KL) + off1 + cf * 2048);              \
    }                                                                              \
    f32x4 sA[4], sB[4];                                                            \
    __builtin_amdgcn_s_setprio(1);                                                 \
    _Pragma("unroll")                                                              \
    for (int cf = 0; cf < 4; ++cf) {                                               \
      f32x4 z = {};                                                                \
      z = __builtin_amdgcn_mfma_f32_16x16x32_f16(ka[cf], qfA0, z, 0, 0, 0);        \
      z = __builtin_amdgcn_mfma_f32_16x16x32_f16(kb[cf], qfA1, z, 0, 0, 0);        \
      sA[cf] = z;                                                                  \
    }                                                                              \
    _Pragma("unroll")                                                              \
    for (int cf = 0; cf < 4; ++cf) {                                               \
      f32x4 z = {};                                                                \
      z = __builtin_amdgcn_mfma_f32_16x16x32_f16(ka[cf], qfB0, z, 0, 0, 0);        \
      z = __builtin_amdgcn_mfma_f32_16x16x32_f16(kb[cf], qfB1, z, 0, 0, 0);        \
      sB[cf] = z;                                                                  \
    }                                                                              \
    __builtin_amdgcn_s_setprio(0);                                                 \
    SMX_GROUP(sA, mrA[T], m2A, lsA, A)                                             \
    SMX_GROUP(sB, mrB[T], m2B, lsB, B)                                             \
    _Pragma("unroll")                                                              \
    for (int ks = 0; ks < 2; ++ks) {                                               \
      int fo = ks ? off1 : off0;                                                   \
      half8 vk[4];                                                                 \
      _Pragma("unroll")                                                            \
      for (int df = 0; df < 4; ++df)                                               \
        vk[df] = *(const half8*)((const char*)(VL) + fo + df * 2048);              \
      half8 pfA = *(const half8*)(pbA + fo);                                       \
      half8 pfB = *(const half8*)(pbB + fo);                                       \
      __builtin_amdgcn_s_setprio(1);                                               \
      _Pragma("unroll")                                                            \
      for (int df = 0; df < 4; ++df)                                               \
        oA[df] = __builtin_amdgcn_mfma_f32_16x16x32_f16(vk[df], pfA, oA[df], 0, 0, 0); \
      _Pragma("unroll")                                                            \
      for (int df = 0; df < 4; ++df)                                               \
        oB[df] = __builtin_amdgcn_mfma_f32_16x16x32_f16(vk[df], pfB, oB[df], 0, 0, 0); \
      __builtin_amdgcn_s_setprio(0);                                               \
    }                                                                              \
    __syncthreads();                                                               \
  }

__launch_bounds__(256, 2)
__global__ void attn_k(const h16* __restrict__ qh, const h16* __restrict__ kh,
                       const h16* __restrict__ vt, const unsigned long long* __restrict__ mp,
                       h16* __restrict__ pO, float* __restrict__ pML) {
    __shared__ h16 K0[4096], K1[4096], V0[4096], V1[4096];
    __shared__ char Ps[16384];                 // per-wave 4KB (2 groups x 2KB)
    const int tid = threadIdx.x;
    const int lane = tid & 63, wid = tid >> 6;
    const int l = lane & 15, g = lane >> 4;
    const int bid = blockIdx.x;
    const int idx = (bid & 7) * 96 + (bid >> 3);   // XCD-contiguous; 3 bh per XCD
    const int bh = idx >> 5;
    const int rem = idx & 31;
    const int qb = rem >> 1, kvh = rem & 1;
    const int q0w = qb * 128 + wid * 32;
    const long base = (long)bh * SS * DKK;
    char* pbA = Ps + wid * 4096;
    char* pbB = pbA + 2048;
    const pk2 one2 = {(__fp16)1.0f, (__fp16)1.0f};

    const int off0 = l * 128 + ((g ^ (l & 7)) << 4);
    const int off1 = l * 128 + (((4 + g) ^ (l & 7)) << 4);
    int pst[4];
#pragma unroll
    for (int cf = 0; cf < 4; ++cf)
        pst[cf] = l * 128 + (((2 * cf + (g >> 1)) ^ (l & 7)) << 4) + (g & 1) * 8;
    const int rr = lane >> 3, sg = (lane & 7) ^ (lane >> 3);
    const int stg0 = wid * 1024 + lane * 8, stg1 = wid * 1024 + 512 + lane * 8;
    const int kvbase = kvh * 1024;             // absolute kv start of this block's half
    const h16* kgl0 = kh + base + (long)(kvbase + wid * 16 + rr) * DKK + sg * 8;
    const h16* kgl1 = kgl0 + 8 * DKK;
    const h16* vgl0 = vt + base + (long)(wid * 16 + rr) * SS + kvbase + sg * 8;
    const h16* vgl1 = vgl0 + 8 * SS;

    half8 qfA0, qfA1, qfB0, qfB1;              // q pre-scaled by K2F
    {
        const h16* qp = qh + base + (long)(q0w + l) * DKK + g * 8;
        qfA0 = *(const half8*)qp;
        qfA1 = *(const half8*)(qp + 32);
        qfB0 = *(const half8*)(qp + 16 * DKK);
        qfB1 = *(const half8*)(qp + 16 * DKK + 32);
    }
    const unsigned long long* mrA = mp + (long)(q0w + l) * (SS / 64) + kvh * 16;
    const unsigned long long* mrB = mrA + 16 * (SS / 64);

    f32x4 oA[4] = {}, oB[4] = {};
    float m2A = -INFINITY, lsA = 0.f, m2B = -INFINITY, lsB = 0.f;
    const float C2 = 1e-6f * 1.44269504f;      // masked value in log2 domain

    // prologue: stage local tile 0
    gl_lds16(kgl0, K0 + stg0);
    gl_lds16(kgl1, K0 + stg1);
    gl_lds16(vgl0, V0 + stg0);
    gl_lds16(vgl1, V0 + stg1);
    __syncthreads();

    for (int it = 0; it < 8; ++it) {
        int t = 2 * it;
        ATTN_TILE(K0, V0, K1, V1, t)
        ATTN_TILE(K1, V1, K0, V0, t + 1)
    }

    // epilogue: reduce lsums, write unnormalized partials + (m,l)
    lsA += __shfl_xor(lsA, 16);
    lsA += __shfl_xor(lsA, 32);
    lsB += __shfl_xor(lsB, 16);
    lsB += __shfl_xor(lsB, 32);
    long prow = ((long)(bh * 2 + kvh) * 2048 + q0w + l);
    h16* pa = pO + (prow << 6) + g * 4;
    h16* pbo = pO + ((prow + 16) << 6) + g * 4;
#pragma unroll
    for (int df = 0; df < 4; ++df) {
        h16x4 vA = {(h16)oA[df][0], (h16)oA[df][1], (h16)oA[df][2], (h16)oA[df][3]};
        h16x4 vB = {(h16)oB[df][0], (h16)oB[df][1], (h16)oB[df][2], (h16)oB[df][3]};
        *(h16x4*)(pa + df * 16) = vA;
        *(h16x4*)(pbo + df * 16) = vB;
    }
    if (g == 0) {
        *(float2*)(pML + prow * 2) = make_float2(m2A, lsA);
        *(float2*)(pML + (prow + 16) * 2) = make_float2(m2B, lsB);
    }
}

// ---------------- output GEMM with fused partial-combine A-staging ----------------
// A row m (=b*2048+q), k-tile h: x = pO[r0][d]*s0 + pO[r1][d]*s1 computed in regs,
// written to the same swizzled LDS slot the gl_lds path used. B stays global_load_lds.
__launch_bounds__(256)
__global__ void out_gemm_k(const h16* __restrict__ pO, const float* __restrict__ pML,
                           const h16* __restrict__ Woh, const float* __restrict__ bo,
                           float* __restrict__ out) {
    __shared__ h16 As[64 * 64];
    __shared__ h16 Bs[64 * 64];
    const int bid = blockIdx.x;                    // 0..767
    const int idx = (bid & 7) * 96 + (bid >> 3);
    const int m0 = (idx / 12) * 64, n0 = (idx % 12) * 64;
    const int tid = threadIdx.x, lane = tid & 63, wid = tid >> 6;
    const int l = lane & 15, gq = lane >> 4;
    const int wr = wid >> 1, wc = wid & 1;
    f32x4 acc[2][2] = {};                          // wave: 32m x 32n

    for (int k0 = 0; k0 < EE; k0 += 64) {
        const int h = k0 >> 6;
#pragma unroll
        for (int it = 0; it < 2; ++it) {           // B: gl_lds as before
            int e = it * 256 + tid;
            int row = e >> 3, slot = e & 7;
            int gsl = (slot ^ (row & 7)) << 3;
            gl_lds16(Woh + (long)(n0 + row) * EE + k0 + gsl, Bs + e * 8);
        }
#pragma unroll
        for (int it = 0; it < 2; ++it) {           // A: reg-staged combine of kv-half partials
            int e = it * 256 + tid;
            int row = e >> 3, slot = e & 7;
            int m = m0 + row;
            int b = m >> 11, q = m & 2047;
            long r0 = ((long)((b * HH + h) * 2) * 2048) + q;
            long r1 = r0 + 2048;
            float2 ml0 = *(const float2*)(pML + r0 * 2);
            float2 ml1 = *(const float2*)(pML + r1 * 2);
            int gsl = (slot ^ (row & 7)) << 3;
            half8 o0 = *(const half8*)(pO + (r0 << 6) + gsl);
            half8 o1 = *(const half8*)(pO + (r1 << 6) + gsl);
            float ms = fmaxf(ml0.x, ml1.x);
            float w0 = __builtin_amdgcn_exp2f(ml0.x - ms);
            float w1 = __builtin_amdgcn_exp2f(ml1.x - ms);
            float inv = 1.0f / (ml0.y * w0 + ml1.y * w1);
            float s0 = w0 * inv, s1 = w1 * inv;
            half8 r;
#pragma unroll
            for (int i = 0; i < 8; ++i)
                r[i] = (h16)((float)o0[i] * s0 + (float)o1[i] * s1);
            *(half8*)(As + e * 8) = r;
        }
        __syncthreads();
#pragma unroll
        for (int ks = 0; ks < 2; ++ks) {
            half8 a[2], b[2];
#pragma unroll
            for (int rf = 0; rf < 2; ++rf) {
                int row = wr * 32 + rf * 16 + l;
                int g = (ks * 4 + gq) ^ (row & 7);
                a[rf] = *(const half8*)((const char*)As + row * 128 + (g << 4));
            }
#pragma unroll
            for (int cf = 0; cf < 2; ++cf) {
                int row = wc * 32 + cf * 16 + l;
                int g = (ks * 4 + gq) ^ (row & 7);
                b[cf] = *(const half8*)((const char*)Bs + row * 128 + (g << 4));
            }
            __builtin_amdgcn_s_setprio(1);
#pragma unroll
            for (int rf = 0; rf < 2; ++rf)
#pragma unroll
                for (int cf = 0; cf < 2; ++cf)
                    acc[rf][cf] = __builtin_amdgcn_mfma_f32_16x16x32_f16(a[rf], b[cf], acc[rf][cf], 0, 0, 0);
            __builtin_amdgcn_s_setprio(0);
        }
        __syncthreads();
    }
#pragma unroll
    for (int rf = 0; rf < 2; ++rf)
#pragma unroll
        for (int cf = 0; cf < 2; ++cf) {
            int n = n0 + wc * 32 + cf * 16 + l;
            float bias = bo[n];
#pragma unroll
            for (int j = 0; j < 4; ++j) {
                int m = m0 + wr * 32 + rf * 16 + gq * 4 + j;
                out[(long)m * EE + n] = acc[rf][cf][j] + bias;
            }
        }
}

extern "C" void kernel_launch(void* const* d_in, const int* in_sizes, int n_in,
                              void* d_out, int out_size, void* d_ws, size_t ws_size,
                              hipStream_t stream) {
    const float* key   = (const float*)d_in[0];
    const float* query = (const float*)d_in[1];
    const float* value = (const float*)d_in[2];
    const int*   mask  = (const int*)d_in[3];
    const float* Wk    = (const float*)d_in[4];
    const float* bk    = (const float*)d_in[5];
    const float* Wo    = (const float*)d_in[6];
    const float* bo    = (const float*)d_in[7];

    char* ws = (char*)d_ws;
    h16* keyh = (h16*)(ws + 0);                    // dead after proj -> pO aliases
    h16* qryh = (h16*)(ws + 6291456);              // dead after proj -> pO aliases
    h16* valh = (h16*)(ws + 12582912);             // dead after proj -> pML aliases
    h16* qh   = (h16*)(ws + 18874368);             // dead after attn
    h16* kh   = (h16*)(ws + 25165824);
    h16* vt   = (h16*)(ws + 31457280);
    h16* Wkh  = (h16*)(ws + 37748736);
    h16* Woh  = (h16*)(ws + 38928384);
    unsigned* mp = (unsigned*)(ws + 40108032);
    h16*  pO  = (h16*)(ws + 0);                    // 24*2*2048*64 fp16 = 12.58 MB
    float* pML = (float*)(ws + 12582912);          // 24*2*2048*2 f32 = 786 KB
    float* out = (float*)d_out;

    hipLaunchKernelGGL(cvtpack_k, dim3(5696), dim3(256), 0, stream,
                       key, query, value, Wk, Wo, keyh, qryh, valh, Wkh, Woh, mask, mp);
    hipLaunchKernelGGL(proj_gemm_k, dim3(1152), dim3(256), 0, stream,
                       keyh, qryh, valh, Wkh, bk, kh, qh, vt);
    hipLaunchKernelGGL(attn_k, dim3(768), dim3(256), 0, stream,
                       qh, kh, vt, (const unsigned long long*)mp, pO, pML);
    hipLaunchKernelGGL(out_gemm_k, dim3(768), dim3(256), 0, stream,
                       pO, pML, Woh, bo, out);
}

// Round 19
// 115.861 us; speedup vs baseline: 1.0575x; 1.0575x over previous
//
#include <hip/hip_runtime.h>

#define BB 2
#define SS 2048
#define EE 768
#define HH 12
#define DKK 64

typedef _Float16 h16;
typedef _Float16 half8 __attribute__((ext_vector_type(8)));
typedef _Float16 h16x4 __attribute__((ext_vector_type(4)));
typedef __fp16 pk2 __attribute__((ext_vector_type(2)));
typedef float f32x4 __attribute__((ext_vector_type(4)));

#define K2F 11.5416173f                        // 8 * log2(e): source multiplies by sqrt(dk)!

// direct global->LDS 16B async copy (linear LDS dest = wave base + lane*16)
__device__ __forceinline__ void gl_lds16(const void* g, void* l) {
    __builtin_amdgcn_global_load_lds(
        (const __attribute__((address_space(1))) unsigned int*)g,
        (__attribute__((address_space(3))) unsigned int*)l, 16, 0, 0);
}

// ---------------- fused: fp32->fp16 convert (blocks 0..5183) + mask packing (5184..5695) ----------------
__global__ void cvtpack_k(const float* __restrict__ sK, const float* __restrict__ sQ,
                          const float* __restrict__ sV, const float* __restrict__ sWk,
                          const float* __restrict__ sWo,
                          h16* __restrict__ dK, h16* __restrict__ dQ, h16* __restrict__ dV,
                          h16* __restrict__ dWk, h16* __restrict__ dWo,
                          const int* __restrict__ mask, unsigned* __restrict__ mp) {
    if (blockIdx.x >= 5184) {                  // mask packing: int32 [S,S] -> 1 bit
        int idx = (blockIdx.x - 5184) * 256 + threadIdx.x;
        int base = idx * 32;
        const int4* m4 = (const int4*)(mask + base);
        unsigned w = 0;
#pragma unroll
        for (int i = 0; i < 8; ++i) {
            int4 v = m4[i];
            if (v.x) w |= 1u << (i * 4 + 0);
            if (v.y) w |= 1u << (i * 4 + 1);
            if (v.z) w |= 1u << (i * 4 + 2);
            if (v.w) w |= 1u << (i * 4 + 3);
        }
        mp[idx] = w;
        return;
    }
    long g = (long)blockIdx.x * 256 + threadIdx.x;
    const float* src;
    h16* dst;
    long off;
    if (g < 393216)        { src = sK;  dst = dK;  off = g; }
    else if (g < 786432)   { src = sQ;  dst = dQ;  off = g - 393216; }
    else if (g < 1179648)  { src = sV;  dst = dV;  off = g - 786432; }
    else if (g < 1253376)  { src = sWk; dst = dWk; off = g - 1179648; }
    else                   { src = sWo; dst = dWo; off = g - 1253376; }
    const float* p = src + off * 8;
    float4 a = *(const float4*)p, b = *(const float4*)(p + 4);
    half8 h = {(h16)a.x, (h16)a.y, (h16)a.z, (h16)a.w,
               (h16)b.x, (h16)b.y, (h16)b.z, (h16)b.w};
    *(half8*)(dst + off * 8) = h;
}

// ---------------- projection GEMM: fp16 in, global_load_lds staging ----------------
__launch_bounds__(256)
__global__ void proj_gemm_k(const h16* __restrict__ keyh, const h16* __restrict__ qryh,
                            const h16* __restrict__ valh, const h16* __restrict__ Wkh,
                            const float* __restrict__ bk,
                            h16* __restrict__ kh, h16* __restrict__ qh, h16* __restrict__ vtp) {
    __shared__ h16 As[64 * 64];                     // 8 KB
    __shared__ h16 Bs[128 * 64];                    // 16 KB
    const int bid = blockIdx.x;                     // 0..1151
    const int idx = (bid & 7) * 144 + (bid >> 3);
    const int z = idx / 384;
    const int rem = idx % 384;
    const int m0 = (rem / 6) * 64, n0 = (rem % 6) * 128;
    const h16* src = (z == 0) ? keyh : ((z == 1) ? qryh : valh);
    const int tid = threadIdx.x, lane = tid & 63, wid = tid >> 6;
    const int l = lane & 15, gq = lane >> 4;
    f32x4 acc[4][2] = {};                           // wave: 64m x 32n

    for (int k0 = 0; k0 < EE; k0 += 64) {
#pragma unroll
        for (int it = 0; it < 2; ++it) {            // A: 64 rows
            int e = it * 256 + tid;
            int row = e >> 3, slot = e & 7;
            gl_lds16(src + (long)(m0 + row) * EE + k0 + ((slot ^ (row & 7)) << 3), As + e * 8);
        }
#pragma unroll
        for (int it = 0; it < 4; ++it) {            // B: 128 rows
            int e = it * 256 + tid;
            int row = e >> 3, slot = e & 7;
            gl_lds16(Wkh + (long)(n0 + row) * EE + k0 + ((slot ^ (row & 7)) << 3), Bs + e * 8);
        }
        __syncthreads();                            // drains vmcnt
#pragma unroll
        for (int ks = 0; ks < 2; ++ks) {
            half8 a[4], b[2];
#pragma unroll
            for (int rf = 0; rf < 4; ++rf) {
                int row = rf * 16 + l;
                int g = (ks * 4 + gq) ^ (row & 7);
                a[rf] = *(const half8*)((const char*)As + row * 128 + (g << 4));
            }
#pragma unroll
            for (int cf = 0; cf < 2; ++cf) {
                int row = wid * 32 + cf * 16 + l;
                int g = (ks * 4 + gq) ^ (row & 7);
                b[cf] = *(const half8*)((const char*)Bs + row * 128 + (g << 4));
            }
            __builtin_amdgcn_s_setprio(1);
#pragma unroll
            for (int rf = 0; rf < 4; ++rf)
#pragma unroll
                for (int cf = 0; cf < 2; ++cf)
                    acc[rf][cf] = __builtin_amdgcn_mfma_f32_16x16x32_f16(a[rf], b[cf], acc[rf][cf], 0, 0, 0);
            __builtin_amdgcn_s_setprio(0);
        }
        __syncthreads();
    }
    if (z == 2) {
        // V: write transposed vt[(b*H+h)*64 + d][s], 4 consecutive s packed
#pragma unroll
        for (int rf = 0; rf < 4; ++rf)
#pragma unroll
            for (int cf = 0; cf < 2; ++cf) {
                int n = n0 + wid * 32 + cf * 16 + l;
                float bias = bk[n];
                int h = n >> 6, d = n & 63;
                int mb = m0 + rf * 16 + gq * 4;
                int b = mb >> 11, s = mb & 2047;
                h16x4 pv = {(h16)(acc[rf][cf][0] + bias), (h16)(acc[rf][cf][1] + bias),
                            (h16)(acc[rf][cf][2] + bias), (h16)(acc[rf][cf][3] + bias)};
                *(h16x4*)(vtp + ((long)((b * HH + h) * 64 + d)) * SS + s) = pv;
            }
    } else {
        h16* dst = (z == 0) ? kh : qh;
        const float qs = (z == 1) ? K2F : 1.0f;     // pre-scale q into exp2 domain
#pragma unroll
        for (int rf = 0; rf < 4; ++rf)
#pragma unroll
            for (int cf = 0; cf < 2; ++cf) {
                int n = n0 + wid * 32 + cf * 16 + l;
                float bias = bk[n];
                int h = n >> 6, d = n & 63;
#pragma unroll
                for (int j = 0; j < 4; ++j) {
                    int m = m0 + rf * 16 + gq * 4 + j;
                    int b = m >> 11, s = m & 2047;
                    dst[(((long)(b * HH + h) * SS + s) << 6) + d] = (h16)((acc[rf][cf][j] + bias) * qs);
                }
            }
    }
}

// ---------------- flash attention: 4 waves x 32 q-rows (2 groups), kv-split-2, partials ----------------
#define SMX_GROUP(S, MW, M2, LS, PB)                                               \
  {                                                                                \
    unsigned long long mw = (MW);                                                  \
    unsigned w0 = (unsigned)mw, w1 = (unsigned)(mw >> 32);                         \
    _Pragma("unroll")                                                              \
    for (int cf = 0; cf < 4; ++cf) {                                               \
      unsigned wcb = (cf & 2) ? w1 : w0;                                           \
      _Pragma("unroll")                                                            \
      for (int j = 0; j < 4; ++j) {                                                \
        unsigned sh = ((cf & 1) << 4) + g * 4 + j;                                 \
        S[cf][j] = ((wcb >> sh) & 1u) ? S[cf][j] : C2;                             \
      }                                                                            \
    }                                                                              \
    float pmax = fmaxf(fmaxf(S[0][0], S[0][1]), fmaxf(S[0][2], S[0][3]));          \
    _Pragma("unroll")                                                              \
    for (int cf = 1; cf < 4; ++cf)                                                 \
      pmax = fmaxf(pmax, fmaxf(fmaxf(S[cf][0], S[cf][1]), fmaxf(S[cf][2], S[cf][3]))); \
    if (!__all(pmax <= (M2) + 11.0f)) {                                            \
      pmax = fmaxf(pmax, __shfl_xor(pmax, 16));                                    \
      pmax = fmaxf(pmax, __shfl_xor(pmax, 32));                                    \
      float mnew = fmaxf((M2), pmax);                                              \
      float alpha = __builtin_amdgcn_exp2f((M2) - mnew);                           \
      _Pragma("unroll")                                                            \
      for (int df = 0; df < 4; ++df)                                               \
        _Pragma("unroll")                                                          \
        for (int j = 0; j < 4; ++j) o##PB[df][j] *= alpha;                         \
      (LS) *= alpha;                                                               \
      (M2) = mnew;                                                                 \
    }                                                                              \
    const float negm2 = -(M2);                                                     \
    float rs = 0.f;                                                                \
    _Pragma("unroll")                                                              \
    for (int cf = 0; cf < 4; ++cf)                                                 \
      _Pragma("unroll")                                                            \
      for (int j = 0; j < 4; ++j) {                                                \
        float p = __builtin_amdgcn_exp2f(S[cf][j] + negm2);                        \
        S[cf][j] = p;                                                              \
        rs += p;                                                                   \
      }                                                                            \
    (LS) += rs;                                                                    \
    _Pragma("unroll")                                                              \
    for (int cf = 0; cf < 4; ++cf) {                                               \
      union { pk2 h[2]; unsigned long long u; } pu;                                \
      pu.h[0] = __builtin_amdgcn_cvt_pkrtz(S[cf][0], S[cf][1]);                    \
      pu.h[1] = __builtin_amdgcn_cvt_pkrtz(S[cf][2], S[cf][3]);                    \
      *(unsigned long long*)(pb##PB + pst[cf]) = pu.u;                             \
    }                                                                              \
  }

#define ATTN_TILE(KL, VL, KN, VN, T)                                               \
  {                                                                                \
    long nko = (long)((((T) + 1) & 15)) * (64 * DKK);                              \
    int nvo = (((T) + 1) & 15) * 64;                                               \
    gl_lds16(kgl0 + nko, (KN) + stg0);                                             \
    gl_lds16(kgl1 + nko, (KN) + stg1);                                             \
    gl_lds16(vgl0 + nvo, (VN) + stg0);                                             \
    gl_lds16(vgl1 + nvo, (VN) + stg1);                                             \
    half8 ka[4], kb[4];                                                            \
    _Pragma("unroll")                                                              \
    for (int cf = 0; cf < 4; ++cf) {                                               \
      ka[cf] = *(const half8*)((const char*)(KL) + off0 + cf * 2048);              \
      kb[cf] = *(const half8*)((const char*)(KL) + off1 + cf * 2048);              \
    }                                                                              \
    f32x4 sA[4], sB[4];                                                            \
    __builtin_amdgcn_s_setprio(1);                                                 \
    _Pragma("unroll")                                                              \
    for (int cf = 0; cf < 4; ++cf) {                                               \
      f32x4 z = {};                                                                \
      z = __builtin_amdgcn_mfma_f32_16x16x32_f16(ka[cf], qfA0, z, 0, 0, 0);        \
      z = __builtin_amdgcn_mfma_f32_16x16x32_f16(kb[cf], qfA1, z, 0, 0, 0);        \
      sA[cf] = z;                                                                  \
    }                                                                              \
    _Pragma("unroll")                                                              \
    for (int cf = 0; cf < 4; ++cf) {                                               \
      f32x4 z = {};                                                                \
      z = __builtin_amdgcn_mfma_f32_16x16x32_f16(ka[cf], qfB0, z, 0, 0, 0);        \
      z = __builtin_amdgcn_mfma_f32_16x16x32_f16(kb[cf], qfB1, z, 0, 0, 0);        \
      sB[cf] = z;                                                                  \
    }                                                                              \
    __builtin_amdgcn_s_setprio(0);                                                 \
    SMX_GROUP(sA, mrA[T], m2A, lsA, A)                                             \
    SMX_GROUP(sB, mrB[T], m2B, lsB, B)                                             \
    _Pragma("unroll")                                                              \
    for (int ks = 0; ks < 2; ++ks) {                                               \
      int fo = ks ? off1 : off0;                                                   \
      half8 vk[4];                                                                 \
      _Pragma("unroll")                                                            \
      for (int df = 0; df < 4; ++df)                                               \
        vk[df] = *(const half8*)((const char*)(VL) + fo + df * 2048);              \
      half8 pfA = *(const half8*)(pbA + fo);                                       \
      half8 pfB = *(const half8*)(pbB + fo);                                       \
      __builtin_amdgcn_s_setprio(1);                                               \
      _Pragma("unroll")                                                            \
      for (int df = 0; df < 4; ++df)                                               \
        oA[df] = __builtin_amdgcn_mfma_f32_16x16x32_f16(vk[df], pfA, oA[df], 0, 0, 0); \
      _Pragma("unroll")                                                            \
      for (int df = 0; df < 4; ++df)                                               \
        oB[df] = __builtin_amdgcn_mfma_f32_16x16x32_f16(vk[df], pfB, oB[df], 0, 0, 0); \
      __builtin_amdgcn_s_setprio(0);                                               \
    }                                                                              \
    __syncthreads();                                                               \
  }

__launch_bounds__(256, 3)
__global__ void attn_k(const h16* __restrict__ qh, const h16* __restrict__ kh,
                       const h16* __restrict__ vt, const unsigned long long* __restrict__ mp,
                       h16* __restrict__ pO, float* __restrict__ pML) {
    __shared__ h16 K0[4096], K1[4096], V0[4096], V1[4096];
    __shared__ char Ps[16384];                 // per-wave 4KB (2 groups x 2KB)
    const int tid = threadIdx.x;
    const int lane = tid & 63, wid = tid >> 6;
    const int l = lane & 15, g = lane >> 4;
    const int bid = blockIdx.x;
    const int idx = (bid & 7) * 96 + (bid >> 3);   // XCD-contiguous; 3 bh per XCD
    const int bh = idx >> 5;
    const int rem = idx & 31;
    const int qb = rem >> 1, kvh = rem & 1;
    const int q0w = qb * 128 + wid * 32;
    const long base = (long)bh * SS * DKK;
    char* pbA = Ps + wid * 4096;
    char* pbB = pbA + 2048;

    const int off0 = l * 128 + ((g ^ (l & 7)) << 4);
    const int off1 = l * 128 + (((4 + g) ^ (l & 7)) << 4);
    int pst[4];
#pragma unroll
    for (int cf = 0; cf < 4; ++cf)
        pst[cf] = l * 128 + (((2 * cf + (g >> 1)) ^ (l & 7)) << 4) + (g & 1) * 8;
    const int rr = lane >> 3, sg = (lane & 7) ^ (lane >> 3);
    const int stg0 = wid * 1024 + lane * 8, stg1 = wid * 1024 + 512 + lane * 8;
    const int kvbase = kvh * 1024;             // absolute kv start of this block's half
    const h16* kgl0 = kh + base + (long)(kvbase + wid * 16 + rr) * DKK + sg * 8;
    const h16* kgl1 = kgl0 + 8 * DKK;
    const h16* vgl0 = vt + base + (long)(wid * 16 + rr) * SS + kvbase + sg * 8;
    const h16* vgl1 = vgl0 + 8 * SS;

    half8 qfA0, qfA1, qfB0, qfB1;              // q pre-scaled by K2F
    {
        const h16* qp = qh + base + (long)(q0w + l) * DKK + g * 8;
        qfA0 = *(const half8*)qp;
        qfA1 = *(const half8*)(qp + 32);
        qfB0 = *(const half8*)(qp + 16 * DKK);
        qfB1 = *(const half8*)(qp + 16 * DKK + 32);
    }
    const unsigned long long* mrA = mp + (long)(q0w + l) * (SS / 64) + kvh * 16;
    const unsigned long long* mrB = mrA + 16 * (SS / 64);

    f32x4 oA[4] = {}, oB[4] = {};
    float m2A = -INFINITY, lsA = 0.f, m2B = -INFINITY, lsB = 0.f;
    const float C2 = 1e-6f * 1.44269504f;      // masked value in log2 domain

    // prologue: stage local tile 0
    gl_lds16(kgl0, K0 + stg0);
    gl_lds16(kgl1, K0 + stg1);
    gl_lds16(vgl0, V0 + stg0);
    gl_lds16(vgl1, V0 + stg1);
    __syncthreads();

    for (int it = 0; it < 8; ++it) {
        int t = 2 * it;
        ATTN_TILE(K0, V0, K1, V1, t)
        ATTN_TILE(K1, V1, K0, V0, t + 1)
    }

    // epilogue: reduce lsums, write unnormalized partials + (m,l)
    lsA += __shfl_xor(lsA, 16);
    lsA += __shfl_xor(lsA, 32);
    lsB += __shfl_xor(lsB, 16);
    lsB += __shfl_xor(lsB, 32);
    long prow = ((long)(bh * 2 + kvh) * 2048 + q0w + l);
    h16* pa = pO + (prow << 6) + g * 4;
    h16* pbo = pO + ((prow + 16) << 6) + g * 4;
#pragma unroll
    for (int df = 0; df < 4; ++df) {
        h16x4 vA = {(h16)oA[df][0], (h16)oA[df][1], (h16)oA[df][2], (h16)oA[df][3]};
        h16x4 vB = {(h16)oB[df][0], (h16)oB[df][1], (h16)oB[df][2], (h16)oB[df][3]};
        *(h16x4*)(pa + df * 16) = vA;
        *(h16x4*)(pbo + df * 16) = vB;
    }
    if (g == 0) {
        float2* mlp = (float2*)(pML + prow * 2);
        *mlp = make_float2(m2A, lsA);
        *(float2*)(pML + (prow + 16) * 2) = make_float2(m2B, lsB);
    }
}

// ---------------- combine: merge the 2 kv-half partials -> xh fp16 ----------------
__global__ void combine_k(const h16* __restrict__ pO, const float* __restrict__ pML,
                          h16* __restrict__ xh) {
    int idx = blockIdx.x * 256 + threadIdx.x;  // 0..393215
    int d8 = idx & 7;
    int q = (idx >> 3) & 2047;
    int bh = idx >> 14;
    long r0 = (long)(bh * 2) * 2048 + q, r1 = r0 + 2048;
    float2 ml0 = *(const float2*)(pML + r0 * 2);
    float2 ml1 = *(const float2*)(pML + r1 * 2);
    float ms = fmaxf(ml0.x, ml1.x);
    float w0 = __builtin_amdgcn_exp2f(ml0.x - ms);
    float w1 = __builtin_amdgcn_exp2f(ml1.x - ms);
    float inv = 1.0f / (ml0.y * w0 + ml1.y * w1);
    float s0 = w0 * inv, s1 = w1 * inv;
    half8 o0 = *(const half8*)(pO + (r0 << 6) + d8 * 8);
    half8 o1 = *(const half8*)(pO + (r1 << 6) + d8 * 8);
    int b = bh / HH, h = bh % HH;
    half8 r;
#pragma unroll
    for (int i = 0; i < 8; ++i)
        r[i] = (h16)((float)o0[i] * s0 + (float)o1[i] * s1);
    *(half8*)(xh + (long)(b * SS + q) * EE + h * 64 + d8 * 8) = r;
}

// ---------------- output GEMM: 64m x 64n tiles, 768 blocks, global_load_lds staging ----------------
__launch_bounds__(256)
__global__ void out_gemm_k(const h16* __restrict__ xh, const h16* __restrict__ Woh,
                           const float* __restrict__ bo, float* __restrict__ out) {
    __shared__ h16 As[64 * 64];
    __shared__ h16 Bs[64 * 64];
    const int bid = blockIdx.x;                    // 0..767
    const int idx = (bid & 7) * 96 + (bid >> 3);
    const int m0 = (idx / 12) * 64, n0 = (idx % 12) * 64;
    const int tid = threadIdx.x, lane = tid & 63, wid = tid >> 6;
    const int l = lane & 15, gq = lane >> 4;
    const int wr = wid >> 1, wc = wid & 1;
    f32x4 acc[2][2] = {};                          // wave: 32m x 32n

    for (int k0 = 0; k0 < EE; k0 += 64) {
#pragma unroll
        for (int it = 0; it < 2; ++it) {
            int e = it * 256 + tid;
            int row = e >> 3, slot = e & 7;
            int gsl = (slot ^ (row & 7)) << 3;
            gl_lds16(xh + (long)(m0 + row) * EE + k0 + gsl, As + e * 8);
            gl_lds16(Woh + (long)(n0 + row) * EE + k0 + gsl, Bs + e * 8);
        }
        __syncthreads();
#pragma unroll
        for (int ks = 0; ks < 2; ++ks) {
            half8 a[2], b[2];
#pragma unroll
            for (int rf = 0; rf < 2; ++rf) {
                int row = wr * 32 + rf * 16 + l;
                int g = (ks * 4 + gq) ^ (row & 7);
                a[rf] = *(const half8*)((const char*)As + row * 128 + (g << 4));
            }
#pragma unroll
            for (int cf = 0; cf < 2; ++cf) {
                int row = wc * 32 + cf * 16 + l;
                int g = (ks * 4 + gq) ^ (row & 7);
                b[cf] = *(const half8*)((const char*)Bs + row * 128 + (g << 4));
            }
            __builtin_amdgcn_s_setprio(1);
#pragma unroll
            for (int rf = 0; rf < 2; ++rf)
#pragma unroll
                for (int cf = 0; cf < 2; ++cf)
                    acc[rf][cf] = __builtin_amdgcn_mfma_f32_16x16x32_f16(a[rf], b[cf], acc[rf][cf], 0, 0, 0);
            __builtin_amdgcn_s_setprio(0);
        }
        __syncthreads();
    }
#pragma unroll
    for (int rf = 0; rf < 2; ++rf)
#pragma unroll
        for (int cf = 0; cf < 2; ++cf) {
            int n = n0 + wc * 32 + cf * 16 + l;
            float bias = bo[n];
#pragma unroll
            for (int j = 0; j < 4; ++j) {
                int m = m0 + wr * 32 + rf * 16 + gq * 4 + j;
                out[(long)m * EE + n] = acc[rf][cf][j] + bias;
            }
        }
}

extern "C" void kernel_launch(void* const* d_in, const int* in_sizes, int n_in,
                              void* d_out, int out_size, void* d_ws, size_t ws_size,
                              hipStream_t stream) {
    const float* key   = (const float*)d_in[0];
    const float* query = (const float*)d_in[1];
    const float* value = (const float*)d_in[2];
    const int*   mask  = (const int*)d_in[3];
    const float* Wk    = (const float*)d_in[4];
    const float* bk    = (const float*)d_in[5];
    const float* Wo    = (const float*)d_in[6];
    const float* bo    = (const float*)d_in[7];

    char* ws = (char*)d_ws;
    h16* keyh = (h16*)(ws + 0);                    // dead after proj -> pO aliases
    h16* qryh = (h16*)(ws + 6291456);              // dead after proj -> pO aliases
    h16* valh = (h16*)(ws + 12582912);             // dead after proj -> pML aliases
    h16* qh   = (h16*)(ws + 18874368);             // dead after attn -> xh aliases
    h16* kh   = (h16*)(ws + 25165824);
    h16* vt   = (h16*)(ws + 31457280);
    h16* Wkh  = (h16*)(ws + 37748736);
    h16* Woh  = (h16*)(ws + 38928384);
    unsigned* mp = (unsigned*)(ws + 40108032);
    h16*  pO  = (h16*)(ws + 0);                    // 24*2*2048*64 fp16 = 12.58 MB
    float* pML = (float*)(ws + 12582912);          // 24*2*2048*2 f32 = 1.57 MB
    h16*  xh  = (h16*)(ws + 18874368);             // combine output (qh region)
    float* out = (float*)d_out;

    hipLaunchKernelGGL(cvtpack_k, dim3(5696), dim3(256), 0, stream,
                       key, query, value, Wk, Wo, keyh, qryh, valh, Wkh, Woh, mask, mp);
    hipLaunchKernelGGL(proj_gemm_k, dim3(1152), dim3(256), 0, stream,
                       keyh, qryh, valh, Wkh, bk, kh, qh, vt);
    hipLaunchKernelGGL(attn_k, dim3(768), dim3(256), 0, stream,
                       qh, kh, vt, (const unsigned long long*)mp, pO, pML);
    hipLaunchKernelGGL(combine_k, dim3(1536), dim3(256), 0, stream, pO, pML, xh);
    hipLaunchKernelGGL(out_gemm_k, dim3(768), dim3(256), 0, stream, xh, Woh, bo, out);
}